// Round 10
// baseline (2697.502 us; speedup 1.0000x reference)
//
#include <hip/hip_runtime.h>
#include <hip/hip_bf16.h>
#include <stdint.h>

#define G_ 4
#define E_ 16
#define C_ 2048
#define H_ 512
#define F_ 2048

typedef __attribute__((ext_vector_type(8))) short bf16x8;
typedef __attribute__((ext_vector_type(4))) float f32x4;
typedef __attribute__((ext_vector_type(16))) float f32x16;
typedef uint32_t u32_glb __attribute__((address_space(1)));
typedef uint32_t u32_lds __attribute__((address_space(3)));

__device__ __forceinline__ ushort f2bf(float f){
  uint u = __float_as_uint(f);
  return (ushort)((u + 0x7FFFu + ((u >> 16) & 1u)) >> 16);  // RNE
}

__device__ __forceinline__ bf16x8 pack8(f32x4 a, f32x4 b){
  union { bf16x8 v; uint u[4]; } p;
  p.u[0] = (uint)f2bf(a[0]) | ((uint)f2bf(a[1]) << 16);
  p.u[1] = (uint)f2bf(a[2]) | ((uint)f2bf(a[3]) << 16);
  p.u[2] = (uint)f2bf(b[0]) | ((uint)f2bf(b[1]) << 16);
  p.u[3] = (uint)f2bf(b[2]) | ((uint)f2bf(b[3]) << 16);
  return p.v;
}

// fast GELU: t*sigmoid(2y), y = 0.79788456(t + 0.044715 t^3).
// |delta| vs exact-erf GELU <= ~3e-4 elementwise -> ~3e-5 RMS after W2 (zero-mean).
__device__ __forceinline__ f32x4 gelu4f(f32x4 v){
  f32x4 r;
  #pragma unroll
  for (int i = 0; i < 4; ++i){
    float t = v[i];
    float y = 0.7978845608f * t * (1.0f + 0.044715f * t * t);
    y = fminf(fmaxf(y, -9.0f), 9.0f);
    float z = __expf(-2.0f * y);
    r[i] = t * __builtin_amdgcn_rcpf(1.0f + z);
  }
  return r;
}

// transpose + fp32->bf16 convert: src [E][R][C] fp32 -> dst [E][C][R] bf16
__global__ void transpose_cvt(const float* __restrict__ src, ushort* __restrict__ dst,
                              int R, int C){
  __shared__ float tile[64][65];
  int c0 = blockIdx.x * 64, r0 = blockIdx.y * 64, e = blockIdx.z;
  int tx = threadIdx.x & 63, ty = threadIdx.x >> 6;   // 256 threads
  const float* s = src + (size_t)e * R * C;
  #pragma unroll
  for (int it = 0; it < 16; ++it){
    int row = ty + it * 4;
    tile[row][tx] = s[(size_t)(r0 + row) * C + (c0 + tx)];
  }
  __syncthreads();
  ushort* d = dst + (size_t)e * C * R;
  #pragma unroll
  for (int it = 0; it < 16; ++it){
    int row = ty + it * 4;
    d[(size_t)(c0 + row) * R + (r0 + tx)] = f2bf(tile[tx][row]);
  }
}

// ffn_fused7: R8 math + cross-chunk pipeline. Per barrier segment:
//   A(t): GEMM2(t) || GEMM1(t+1) (interleaved MFMA), W2_WRITE(t+1), sEx publish
//   B(t): GELU(t+1)->sPa, W2LD(t+2), W1-DMA(t+3), counted vmcnt
// Raw s_barrier + lgkmcnt(0); vmcnt never drained to 0 mid-loop (T3/T4).
__global__ __launch_bounds__(512, 2) void ffn_fused7(
    const float* __restrict__ x,      // [G][E][C][H] fp32
    const float* __restrict__ b1,     // [E][F] fp32
    const float* __restrict__ b2,     // [E][H] fp32
    const ushort* __restrict__ w1t,   // [E][F][H] bf16
    const ushort* __restrict__ w2t,   // [E][H][F] bf16
    float* __restrict__ out){         // [G][E][C][H] fp32
  __shared__ ushort sW1[2][32 * 512];   // 64 KB, linear, content XOR key=(row&31)<<4
  __shared__ ushort sW2b[2][512 * 32];  // 64 KB, [h] 64B rows, 16B slots q ^ ((h>>1)&3)
  __shared__ f32x4  sEx[1024];          // 16 KB
  __shared__ uchar  sPaB[4 * 4096];     //  8 KB [tg][slot][tok]16B

  const int tid  = threadIdx.x;
  const int lane = tid & 63;
  const int wv   = tid >> 6;
  const int hi   = lane >> 5;
  const int t31  = lane & 31;
  const int tg   = wv >> 1;
  const int kh   = wv & 1;

  const int bid  = (blockIdx.x & 7) * 128 + (blockIdx.x >> 3);
  const int e    = bid >> 6;
  const int mb   = bid & 63;
  const int n0   = mb * 128;
  const int g    = n0 >> 11;
  const int c0   = n0 & (C_ - 1);

  // X fragments (own K-half): k = kh*256 + kk*16 + hi*8 + j
  const float* xr = x + ((size_t)(g * E_ + e) * C_ + (c0 + tg * 32 + t31)) * H_
                  + kh * 256 + hi * 8;
  bf16x8 xf[16];
  #pragma unroll
  for (int kk = 0; kk < 16; ++kk){
    f32x4 fa = *(const f32x4*)(xr + kk * 16);
    f32x4 fb = *(const f32x4*)(xr + kk * 16 + 4);
    xf[kk] = pack8(fa, fb);
  }

  f32x16 acc2[8];
  #pragma unroll
  for (int ht = 0; ht < 8; ++ht)
    #pragma unroll
    for (int q = 0; q < 16; ++q) acc2[ht][q] = 0.f;

  const ushort* w1e = w1t + (size_t)e * F_ * H_;
  const ushort* w2e = w2t + (size_t)e * H_ * F_;
  uint4 w2r[4];
  f32x16 acc1;

  #define STAGE_W1(F0, NB)                                                       \
    { _Pragma("unroll")                                                          \
      for (int it = 0; it < 4; ++it){                                            \
        int row = wv + it * 8;                                                   \
        const ushort* gsrc = w1e + (size_t)((F0) + row) * H_                     \
                           + (((lane * 16) ^ (row << 4)) >> 1);                  \
        __builtin_amdgcn_global_load_lds((const u32_glb*)(uintptr_t)gsrc,        \
            (u32_lds*)(uintptr_t)(&sW1[(NB)][row * 512]), 16, 0, 0);             \
      } }
  #define STAGE_W2_ISSUE(F0)                                                     \
    { _Pragma("unroll")                                                          \
      for (int i = 0; i < 4; ++i){                                               \
        int h = 128 * i + (tid >> 2);                                            \
        w2r[i] = *(const uint4*)(w2e + (size_t)h * F_ + (F0) + (tid & 3) * 8);   \
      } }
  #define STAGE_W2_WRITE(NB)                                                     \
    { _Pragma("unroll")                                                          \
      for (int i = 0; i < 4; ++i){                                               \
        int h = 128 * i + (tid >> 2);                                            \
        int slot = (tid & 3) ^ ((h >> 1) & 3);                                   \
        *(uint4*)((char*)&sW2b[(NB)][0] + h * 64 + slot * 16) = w2r[i];          \
      } }
  #define GEMM1_ONLY(NB)                                                         \
    { const char* rb1 = (const char*)&sW1[(NB)][0] + t31 * 1024;                 \
      _Pragma("unroll")                                                          \
      for (int i = 0; i < 16; ++i){                                              \
        int kb = (kh * 512 + i * 32 + hi * 16) ^ (t31 << 4);                     \
        bf16x8 afr = *(const bf16x8*)(rb1 + kb);                                 \
        acc1 = __builtin_amdgcn_mfma_f32_32x32x16_bf16(afr, xf[i], acc1, 0,0,0); \
      } }
  #define PUBLISH_EX()                                                           \
    { f32x4 e0, e1;                                                              \
      if (kh == 0){                                                              \
        e0 = (f32x4){acc1[8],acc1[9],acc1[10],acc1[11]};                         \
        e1 = (f32x4){acc1[12],acc1[13],acc1[14],acc1[15]};                       \
      } else {                                                                   \
        e0 = (f32x4){acc1[0],acc1[1],acc1[2],acc1[3]};                           \
        e1 = (f32x4){acc1[4],acc1[5],acc1[6],acc1[7]};                           \
      }                                                                          \
      int exb = (tg * 2 + kh) * 64 + lane;                                       \
      sEx[exb] = e0; sEx[512 + exb] = e1; }
  #define GELU_PUBLISH(F0)                                                       \
    { int exr = (tg * 2 + (1 - kh)) * 64 + lane;                                 \
      f32x4 p0 = sEx[exr], p1 = sEx[512 + exr];                                  \
      f32x4 o0, o1;                                                              \
      if (kh == 0){                                                              \
        o0 = (f32x4){acc1[0],acc1[1],acc1[2],acc1[3]};                           \
        o1 = (f32x4){acc1[4],acc1[5],acc1[6],acc1[7]};                           \
      } else {                                                                   \
        o0 = (f32x4){acc1[8],acc1[9],acc1[10],acc1[11]};                         \
        o1 = (f32x4){acc1[12],acc1[13],acc1[14],acc1[15]};                       \
      }                                                                          \
      o0 = o0 + p0; o1 = o1 + p1;                                                \
      const float* b1p = b1 + (size_t)e * F_ + (F0) + kh * 16 + 4 * hi;          \
      f32x4 ba = *(const f32x4*)(b1p);                                           \
      f32x4 bb = *(const f32x4*)(b1p + 8);                                       \
      f32x4 g0 = gelu4f(o0 + ba), g1 = gelu4f(o1 + bb);                          \
      uint4 pw;                                                                  \
      pw.x = (uint)f2bf(g0[0]) | ((uint)f2bf(g0[1]) << 16);                      \
      pw.y = (uint)f2bf(g0[2]) | ((uint)f2bf(g0[3]) << 16);                      \
      pw.z = (uint)f2bf(g1[0]) | ((uint)f2bf(g1[1]) << 16);                      \
      pw.w = (uint)f2bf(g1[2]) | ((uint)f2bf(g1[3]) << 16);                      \
      *(uint4*)(sPaB + tg * 4096 + (kh * 2 + hi) * 512 + t31 * 16) = pw; }

  // ================= prologue =================
  STAGE_W2_ISSUE(0)                    // W2LD(0)
  STAGE_W1(0, 0)                       // DMA(0)
  STAGE_W2_WRITE(0)                    // waits W2LD(0), DMA(0) flies
  STAGE_W1(32, 1)                      // DMA(1)
  asm volatile("s_waitcnt vmcnt(4)" ::: "memory");   // DMA(0) landed
  asm volatile("s_waitcnt lgkmcnt(0)" ::: "memory");
  __builtin_amdgcn_s_barrier();
  __builtin_amdgcn_sched_barrier(0);
  #pragma unroll
  for (int q = 0; q < 16; ++q) acc1[q] = 0.f;
  GEMM1_ONLY(0)                        // G1(0)
  PUBLISH_EX()
  asm volatile("s_waitcnt lgkmcnt(0)" ::: "memory");
  __builtin_amdgcn_s_barrier();        // B1(-1)
  GELU_PUBLISH(0)
  STAGE_W2_ISSUE(32)                   // W2LD(1)
  STAGE_W1(64, 0)                      // DMA(2) -> sW1[0]
  asm volatile("s_waitcnt vmcnt(8)" ::: "memory");   // DMA(1) landed
  asm volatile("s_waitcnt lgkmcnt(0)" ::: "memory");
  __builtin_amdgcn_s_barrier();        // B2(-1)
  __builtin_amdgcn_sched_barrier(0);

  // ================= main pipeline: t = 0..62 =================
  for (int t = 0; t < 63; ++t){
    const int cur = t & 1, nxt = cur ^ 1;
    // ---- segment A: G2(t) || G1(t+1) ----
    const uchar* pab = sPaB + tg * 4096 + t31 * 16 + hi * 8;
    bf16x8 af0, af1;
    {
      uint2 u0 = *(const uint2*)(pab);
      uint2 u1 = *(const uint2*)(pab + 512);
      uint2 u2 = *(const uint2*)(pab + 1024);
      uint2 u3 = *(const uint2*)(pab + 1536);
      union { bf16x8 v; uint u[4]; } A;
      A.u[0] = u0.x; A.u[1] = u0.y; A.u[2] = u1.x; A.u[3] = u1.y; af0 = A.v;
      A.u[0] = u2.x; A.u[1] = u2.y; A.u[2] = u3.x; A.u[3] = u3.y; af1 = A.v;
    }
    #pragma unroll
    for (int q = 0; q < 16; ++q) acc1[q] = 0.f;
    {
      const char* rb1  = (const char*)&sW1[nxt][0] + t31 * 1024;
      const char* wbb  = (const char*)&sW2b[cur][0] + (kh * 256 + t31) * 64;
      const int   key2 = (t31 >> 1) & 3;
      __builtin_amdgcn_s_setprio(1);
      #pragma unroll
      for (int i = 0; i < 16; ++i){
        int kb = (kh * 512 + i * 32 + hi * 16) ^ (t31 << 4);
        bf16x8 afr = *(const bf16x8*)(rb1 + kb);
        acc1 = __builtin_amdgcn_mfma_f32_32x32x16_bf16(afr, xf[i], acc1, 0, 0, 0);
        bf16x8 bfr = *(const bf16x8*)(wbb + (i >> 1) * (32 * 64)
                                      + 16 * (((i & 1) * 2 + hi) ^ key2));
        acc2[i >> 1] = __builtin_amdgcn_mfma_f32_32x32x16_bf16(
            (i & 1) ? af1 : af0, bfr, acc2[i >> 1], 0, 0, 0);
      }
      __builtin_amdgcn_s_setprio(0);
    }
    STAGE_W2_WRITE(nxt)                // waits W2LD(t+1), DMA(t+2) flies
    PUBLISH_EX()
    asm volatile("s_waitcnt lgkmcnt(0)" ::: "memory");
    __builtin_amdgcn_s_barrier();      // B1
    // ---- phase B: GELU(t+1) + staging ----
    GELU_PUBLISH((t + 1) * 32)
    if (t <= 61) STAGE_W2_ISSUE((t + 2) * 32)          // W2LD(t+2)
    if (t <= 60) STAGE_W1((t + 3) * 32, nxt)           // DMA(t+3) -> just-read buf
    if (t < 61)      { asm volatile("s_waitcnt vmcnt(8)" ::: "memory"); }
    else if (t == 61){ asm volatile("s_waitcnt vmcnt(4)" ::: "memory"); }
    else             { asm volatile("s_waitcnt vmcnt(0)" ::: "memory"); }
    asm volatile("s_waitcnt lgkmcnt(0)" ::: "memory");
    __builtin_amdgcn_s_barrier();      // B2
    __builtin_amdgcn_sched_barrier(0);
  }

  // ================= final: G2(63) =================
  {
    const uchar* pab = sPaB + tg * 4096 + t31 * 16 + hi * 8;
    bf16x8 af0, af1;
    {
      uint2 u0 = *(const uint2*)(pab);
      uint2 u1 = *(const uint2*)(pab + 512);
      uint2 u2 = *(const uint2*)(pab + 1024);
      uint2 u3 = *(const uint2*)(pab + 1536);
      union { bf16x8 v; uint u[4]; } A;
      A.u[0] = u0.x; A.u[1] = u0.y; A.u[2] = u1.x; A.u[3] = u1.y; af0 = A.v;
      A.u[0] = u2.x; A.u[1] = u2.y; A.u[2] = u3.x; A.u[3] = u3.y; af1 = A.v;
    }
    const char* wbb  = (const char*)&sW2b[1][0] + (kh * 256 + t31) * 64;
    const int   key2 = (t31 >> 1) & 3;
    __builtin_amdgcn_s_setprio(1);
    #pragma unroll
    for (int i = 0; i < 16; ++i){
      bf16x8 bfr = *(const bf16x8*)(wbb + (i >> 1) * (32 * 64)
                                    + 16 * (((i & 1) * 2 + hi) ^ key2));
      acc2[i >> 1] = __builtin_amdgcn_mfma_f32_32x32x16_bf16(
          (i & 1) ? af1 : af0, bfr, acc2[i >> 1], 0, 0, 0);
    }
    __builtin_amdgcn_s_setprio(0);
  }

  // ---- epilogue: D2 col = h (t31), row = (q&3)+8*(q>>2)+4*hi ----
  const size_t obase = (size_t)(g * E_ + e) * C_ + c0 + tg * 32;
  #pragma unroll
  for (int ht = 0; ht < 8; ++ht){
    const int h  = kh * 256 + ht * 32 + t31;
    const float bb = b2[(size_t)e * H_ + h];
    #pragma unroll
    for (int q = 0; q < 16; ++q){
      const int row = (q & 3) + 8 * (q >> 2) + 4 * hi;
      out[(obase + row) * H_ + h] = acc2[ht][q] + bb;
    }
  }
  #undef STAGE_W1
  #undef STAGE_W2_ISSUE
  #undef STAGE_W2_WRITE
  #undef GEMM1_ONLY
  #undef PUBLISH_EX
  #undef GELU_PUBLISH
}

extern "C" void kernel_launch(void* const* d_in, const int* in_sizes, int n_in,
                              void* d_out, int out_size, void* d_ws, size_t ws_size,
                              hipStream_t stream){
  const float *x = nullptr, *b1 = nullptr, *b2 = nullptr;
  const float* w12[2] = {nullptr, nullptr}; int nw = 0;
  for (int i = 0; i < n_in; ++i){
    long s = (long)in_sizes[i];
    if      (s == (long)G_ * E_ * C_ * H_) x = (const float*)d_in[i];
    else if (s == (long)E_ * H_ * F_) { if (nw < 2) w12[nw++] = (const float*)d_in[i]; }
    else if (s == (long)E_ * F_) b1 = (const float*)d_in[i];
    else if (s == (long)E_ * H_) b2 = (const float*)d_in[i];
  }
  const float* w1 = w12[0];
  const float* w2 = w12[1];
  if (!x || !w1 || !w2 || !b1 || !b2){
    x  = (const float*)d_in[0];
    w1 = (const float*)d_in[1];
    b1 = (const float*)d_in[2];
    w2 = (const float*)d_in[3];
    b2 = (const float*)d_in[4];
  }

  ushort* w1t = (ushort*)d_ws;                       // [E][F][H] bf16
  ushort* w2t = w1t + (size_t)E_ * F_ * H_;          // [E][H][F] bf16

  transpose_cvt<<<dim3(F_ / 64, H_ / 64, E_), dim3(256), 0, stream>>>(w1, w1t, H_, F_);
  transpose_cvt<<<dim3(H_ / 64, F_ / 64, E_), dim3(256), 0, stream>>>(w2, w2t, F_, H_);

  ffn_fused7<<<dim3(E_ * 64), dim3(512), 0, stream>>>(x, b1, b2, w1t, w2t, (float*)d_out);
}

// Round 11
// 1074.795 us; speedup vs baseline: 2.5098x; 2.5098x over previous
//
#include <hip/hip_runtime.h>
#include <hip/hip_bf16.h>
#include <stdint.h>

#define G_ 4
#define E_ 16
#define C_ 2048
#define H_ 512
#define F_ 2048

typedef __attribute__((ext_vector_type(8))) short bf16x8;
typedef __attribute__((ext_vector_type(4))) float f32x4;
typedef uint32_t u32_glb __attribute__((address_space(1)));
typedef uint32_t u32_lds __attribute__((address_space(3)));

__device__ __forceinline__ ushort f2bf(float f){
  uint u = __float_as_uint(f);
  return (ushort)((u + 0x7FFFu + ((u >> 16) & 1u)) >> 16);  // RNE
}

__device__ __forceinline__ bf16x8 pack8(f32x4 a, f32x4 b){
  union { bf16x8 v; uint u[4]; } p;
  p.u[0] = (uint)f2bf(a[0]) | ((uint)f2bf(a[1]) << 16);
  p.u[1] = (uint)f2bf(a[2]) | ((uint)f2bf(a[3]) << 16);
  p.u[2] = (uint)f2bf(b[0]) | ((uint)f2bf(b[1]) << 16);
  p.u[3] = (uint)f2bf(b[2]) | ((uint)f2bf(b[3]) << 16);
  return p.v;
}

// fast GELU: t*sigmoid(2y), y = 0.79788456(t + 0.044715 t^3).
__device__ __forceinline__ f32x4 gelu4f(f32x4 v){
  f32x4 r;
  #pragma unroll
  for (int i = 0; i < 4; ++i){
    float t = v[i];
    float y = 0.7978845608f * t * (1.0f + 0.044715f * t * t);
    y = fminf(fmaxf(y, -9.0f), 9.0f);
    float z = __expf(-2.0f * y);
    r[i] = t * __builtin_amdgcn_rcpf(1.0f + z);
  }
  return r;
}

// transpose + fp32->bf16 convert: src [E][R][C] fp32 -> dst [E][C][R] bf16
__global__ void transpose_cvt(const float* __restrict__ src, ushort* __restrict__ dst,
                              int R, int C){
  __shared__ float tile[64][65];
  int c0 = blockIdx.x * 64, r0 = blockIdx.y * 64, e = blockIdx.z;
  int tx = threadIdx.x & 63, ty = threadIdx.x >> 6;   // 256 threads
  const float* s = src + (size_t)e * R * C;
  #pragma unroll
  for (int it = 0; it < 16; ++it){
    int row = ty + it * 4;
    tile[row][tx] = s[(size_t)(r0 + row) * C + (c0 + tx)];
  }
  __syncthreads();
  ushort* d = dst + (size_t)e * C * R;
  #pragma unroll
  for (int it = 0; it < 16; ++it){
    int row = ty + it * 4;
    d[(size_t)(c0 + row) * R + (r0 + tx)] = f2bf(tile[tx][row]);
  }
}

// ffn_fused8: BM=64, 8 waves = 4 tg(16 tok) x 2 hh (f-half in G1 / h-half in G2).
// All weight staging via global_load_lds (pre-swizzled sources). Per chunk:
// [prefetch t+1] -> G1 (16 MFMA, split acc) -> GELU -> pa write -> B_pa ->
// pa b128 read -> G2 (16 MFMA, 16 indep accs) -> vmcnt(0) -> B_buf.
// Low reg pressure (~190): no spill, slack for scheduler.
__global__ __launch_bounds__(512, 2) void ffn_fused8(
    const float* __restrict__ x,      // [G][E][C][H] fp32
    const float* __restrict__ b1,     // [E][F] fp32
    const float* __restrict__ b2,     // [E][H] fp32
    const ushort* __restrict__ w1t,   // [E][F][H] bf16
    const ushort* __restrict__ w2t,   // [E][H][F] bf16
    float* __restrict__ out){         // [G][E][C][H] fp32
  __shared__ ushort sW1[2][32 * 512];   // 2x32KB [f-row][h], content XOR key=(row&7)<<4
  __shared__ ushort sW2[2][512 * 32];   // 2x32KB [h] 64B rows, 16B slot q^((h>>1)&3)
  __shared__ uchar  sPa[4096];          // [tok 64][f 32] bf16

  const int tid  = threadIdx.x;
  const int lane = tid & 63;
  const int wv   = tid >> 6;          // 0..7
  const int l15  = lane & 15;
  const int lg   = lane >> 4;         // 0..3
  const int tg   = wv >> 1;           // token group (16 tokens)
  const int hh   = wv & 1;            // f-half (G1) / h-half (G2)

  // XCD-aware bijective swizzle: 2048 blocks = 8 XCDs x 256
  const int bid  = (blockIdx.x & 7) * 256 + (blockIdx.x >> 3);
  const int e    = bid >> 7;          // 128 blocks/expert
  const int mb   = bid & 127;
  const int n0   = mb * 64;
  const int g    = n0 >> 11;          // 64 | 2048
  const int c0   = n0 & (C_ - 1);

  // X fragments: lane's token = c0 + tg*16 + l15, full K; k = kk*32 + lg*8 + j
  const float* xr = x + ((size_t)(g * E_ + e) * C_ + (c0 + tg * 16 + l15)) * H_;
  bf16x8 xf[16];
  #pragma unroll
  for (int kk = 0; kk < 16; ++kk){
    f32x4 fa = *(const f32x4*)(xr + kk * 32 + lg * 8);
    f32x4 fb = *(const f32x4*)(xr + kk * 32 + lg * 8 + 4);
    xf[kk] = pack8(fa, fb);
  }

  f32x4 acc2[16];                     // 16 tok x 256 h (hh half) -> 64 VGPR, FINAL
  #pragma unroll
  for (int ht = 0; ht < 16; ++ht) acc2[ht] = (f32x4){0.f, 0.f, 0.f, 0.f};

  const ushort* w1e = w1t + (size_t)e * F_ * H_;
  const ushort* w2e = w2t + (size_t)e * H_ * F_;
  const float*  b1e = b1  + (size_t)e * F_ + hh * 16 + lg * 4;

  // W1 DMA: 4 instr/wave, rows wv+8it, linear dest, pre-swizzled source
  #define STAGE_W1(F0, NB)                                                       \
    { _Pragma("unroll")                                                          \
      for (int it = 0; it < 4; ++it){                                            \
        int row = wv + it * 8;                                                   \
        const ushort* gsrc = w1e + (size_t)((F0) + row) * H_                     \
                           + (((lane * 16) ^ ((row & 7) << 4)) >> 1);            \
        __builtin_amdgcn_global_load_lds((const u32_glb*)(uintptr_t)gsrc,        \
            (u32_lds*)(uintptr_t)(&sW1[(NB)][row * 512]), 16, 0, 0);             \
      } }
  // W2 DMA: 4 instr/wave, 16 h-rows each, slot content pre-permuted in source
  #define STAGE_W2(F0, NB)                                                       \
    { _Pragma("unroll")                                                          \
      for (int it = 0; it < 4; ++it){                                            \
        int hb = (wv * 4 + it) * 16;                                             \
        int h  = hb + (lane >> 2);                                               \
        int q  = lane & 3;                                                       \
        const ushort* gsrc = w2e + (size_t)h * F_ + (F0)                         \
                           + ((q ^ ((h >> 1) & 3)) * 8);                         \
        __builtin_amdgcn_global_load_lds((const u32_glb*)(uintptr_t)gsrc,        \
            (u32_lds*)(uintptr_t)(&sW2[(NB)][hb * 32]), 16, 0, 0);               \
      } }

  // ---- prologue: stage chunk 0 ----
  f32x4 b1cur = *(const f32x4*)(b1e);
  STAGE_W1(0, 0)
  STAGE_W2(0, 0)
  asm volatile("s_waitcnt vmcnt(0)" ::: "memory");
  asm volatile("s_waitcnt lgkmcnt(0)" ::: "memory");
  __builtin_amdgcn_s_barrier();

  const int r1   = hh * 16 + l15;     // G1 A-row (f within chunk)
  const int sw1  = (r1 & 7) << 4;
  const char* paw = (const char*)sPa + (tg * 16 + l15) * 64;

  for (int t = 0; t < 64; ++t){
    const int cur = t & 1, nxt = cur ^ 1;
    f32x4 b1nxt = b1cur;
    if (t < 63){
      b1nxt = *(const f32x4*)(b1e + (t + 1) * 32);
      STAGE_W1((t + 1) * 32, nxt)     // into buffer last read at chunk t-1
      STAGE_W2((t + 1) * 32, nxt)
    }

    // ---- G1: 16 MFMA, two independent chains ----
    f32x4 a1a = (f32x4){0.f,0.f,0.f,0.f};
    f32x4 a1b = (f32x4){0.f,0.f,0.f,0.f};
    {
      const char* rb = (const char*)&sW1[cur][0] + r1 * 1024;
      __builtin_amdgcn_s_setprio(1);
      #pragma unroll
      for (int kk = 0; kk < 16; ++kk){
        bf16x8 afr = *(const bf16x8*)(rb + ((kk * 64 + lg * 16) ^ sw1));
        if (kk & 1) a1b = __builtin_amdgcn_mfma_f32_16x16x32_bf16(afr, xf[kk], a1b, 0, 0, 0);
        else        a1a = __builtin_amdgcn_mfma_f32_16x16x32_bf16(afr, xf[kk], a1a, 0, 0, 0);
      }
      __builtin_amdgcn_s_setprio(0);
    }

    // ---- bias + GELU (lane: f = f0 + hh*16 + lg*4 + i, tok = tg*16 + l15) ----
    {
      f32x4 gv = gelu4f((a1a + a1b) + b1cur);
      uint2 pw;
      pw.x = (uint)f2bf(gv[0]) | ((uint)f2bf(gv[1]) << 16);
      pw.y = (uint)f2bf(gv[2]) | ((uint)f2bf(gv[3]) << 16);
      *(uint2*)((char*)paw + hh * 32 + lg * 8) = pw;
    }
    asm volatile("s_waitcnt lgkmcnt(0)" ::: "memory");
    __builtin_amdgcn_s_barrier();                      // B_pa

    // ---- G2: A = pa (b128, k = lg*8+j = f), B = W2 rows, 16 indep accs ----
    {
      bf16x8 paf = *(const bf16x8*)(paw + lg * 16);
      const char* wb = (const char*)&sW2[cur][0];
      __builtin_amdgcn_s_setprio(1);
      #pragma unroll
      for (int ht = 0; ht < 16; ++ht){
        int h = hh * 256 + ht * 16 + l15;
        bf16x8 bfr = *(const bf16x8*)(wb + h * 64 + 16 * (lg ^ ((h >> 1) & 3)));
        acc2[ht] = __builtin_amdgcn_mfma_f32_16x16x32_bf16(paf, bfr, acc2[ht], 0, 0, 0);
      }
      __builtin_amdgcn_s_setprio(0);
    }
    asm volatile("s_waitcnt vmcnt(0)" ::: "memory");   // DMA(t+1) landed (issued ~chunk ago)
    asm volatile("s_waitcnt lgkmcnt(0)" ::: "memory");
    __builtin_amdgcn_s_barrier();                      // B_buf
    b1cur = b1nxt;
  }

  // ---- epilogue: D2 col = l15 (h), row = lg*4+i (token) ----
  const size_t ob = (size_t)(g * E_ + e) * C_ + c0 + tg * 16 + lg * 4;
  #pragma unroll
  for (int ht = 0; ht < 16; ++ht){
    const int h  = hh * 256 + ht * 16 + l15;
    const float bb = b2[(size_t)e * H_ + h];
    #pragma unroll
    for (int i = 0; i < 4; ++i)
      out[(ob + i) * H_ + h] = acc2[ht][i] + bb;
  }
  #undef STAGE_W1
  #undef STAGE_W2
}

extern "C" void kernel_launch(void* const* d_in, const int* in_sizes, int n_in,
                              void* d_out, int out_size, void* d_ws, size_t ws_size,
                              hipStream_t stream){
  const float *x = nullptr, *b1 = nullptr, *b2 = nullptr;
  const float* w12[2] = {nullptr, nullptr}; int nw = 0;
  for (int i = 0; i < n_in; ++i){
    long s = (long)in_sizes[i];
    if      (s == (long)G_ * E_ * C_ * H_) x = (const float*)d_in[i];
    else if (s == (long)E_ * H_ * F_) { if (nw < 2) w12[nw++] = (const float*)d_in[i]; }
    else if (s == (long)E_ * F_) b1 = (const float*)d_in[i];
    else if (s == (long)E_ * H_) b2 = (const float*)d_in[i];
  }
  const float* w1 = w12[0];
  const float* w2 = w12[1];
  if (!x || !w1 || !w2 || !b1 || !b2){
    x  = (const float*)d_in[0];
    w1 = (const float*)d_in[1];
    b1 = (const float*)d_in[2];
    w2 = (const float*)d_in[3];
    b2 = (const float*)d_in[4];
  }

  ushort* w1t = (ushort*)d_ws;                       // [E][F][H] bf16
  ushort* w2t = w1t + (size_t)E_ * F_ * H_;          // [E][H][F] bf16

  transpose_cvt<<<dim3(F_ / 64, H_ / 64, E_), dim3(256), 0, stream>>>(w1, w1t, H_, F_);
  transpose_cvt<<<dim3(H_ / 64, F_ / 64, E_), dim3(256), 0, stream>>>(w2, w2t, F_, H_);

  ffn_fused8<<<dim3(2048), dim3(512), 0, stream>>>(x, b1, b2, w1t, w2t, (float*)d_out);
}